// Round 7
// baseline (587.811 us; speedup 1.0000x reference)
//
#include <hip/hip_runtime.h>

// ---------------------------------------------------------------------------
// FastSelfAttention on MI355X (gfx950), round 7.
// B=8, S=4096, D=1024, H=16, DH=64.
// R7: GEMM rebuilt around LDS-traffic reduction: 256x128 tile, 4 waves,
// A-only LDS (64 KiB dbuf -> 2 blocks/CU), B streamed L2->registers via
// inline-asm global_load_dwordx4 with manual counted vmcnt. A re-read x2
// (was x4), B re-read x0 through LDS. LDS-staged coalesced epilogues kept.
// ---------------------------------------------------------------------------

typedef unsigned short u16;
typedef float f32x4 __attribute__((ext_vector_type(4)));
typedef short bf16x8 __attribute__((ext_vector_type(8)));

#define DEV __device__ __forceinline__

DEV u16 f2bf(float f) {
  union { float f; unsigned u; } c; c.f = f;
  return (u16)((c.u + 0x7FFFu + ((c.u >> 16) & 1u)) >> 16);
}
DEV float bf2f(u16 h) {
  union { unsigned u; float f; } c; c.u = ((unsigned)h) << 16;
  return c.f;
}

#define SBAR_  __builtin_amdgcn_s_barrier()
#define SB0_   __builtin_amdgcn_sched_barrier(0)
// rule #18: sched_barrier(0) after inline-asm waits so consumers can't hoist
#define LGKM0_  do { asm volatile("s_waitcnt lgkmcnt(0)" ::: "memory"); SB0_; } while (0)
#define VMCNT8_ do { asm volatile("s_waitcnt vmcnt(8)" ::: "memory"); SB0_; } while (0)
#define VMCNT0_ do { asm volatile("s_waitcnt vmcnt(0)" ::: "memory"); SB0_; } while (0)

// 16B global load to 4 VGPRs, manually vmcnt-managed (compiler-invisible data)
DEV bf16x8 gload16(const u16* p) {
  bf16x8 r;
  asm volatile("global_load_dwordx4 %0, %1, off"
               : "=v"(r) : "v"(p) : "memory");
  return r;
}

// --- f32 -> bf16 bulk convert ----------------------------------------------
__global__ __launch_bounds__(256) void k_cvt(const float* __restrict__ in,
                                             u16* __restrict__ out, int n4) {
  int i = blockIdx.x * 256 + threadIdx.x;
  const int stride = gridDim.x * 256;
  for (; i < n4; i += stride) {
    float4 v = reinterpret_cast<const float4*>(in)[i];
    ushort4 o;
    o.x = f2bf(v.x); o.y = f2bf(v.y); o.z = f2bf(v.z); o.w = f2bf(v.w);
    reinterpret_cast<ushort4*>(out)[i] = o;
  }
}

// --- W (K,N) f32 -> W^T (N,K) bf16, 3 weights in one launch (z selects) ----
__global__ __launch_bounds__(256) void k_transw(const float* __restrict__ Wq,
                                                const float* __restrict__ Wk,
                                                const float* __restrict__ Wt,
                                                u16* __restrict__ Wqkt,
                                                u16* __restrict__ Wtt) {
  __shared__ float tile[32][33];
  const int z = blockIdx.z;
  const float* W = (z == 0) ? Wq : (z == 1) ? Wk : Wt;
  u16* D = (z == 0) ? Wqkt : (z == 1) ? (Wqkt + 1024 * 1024) : Wtt;
  const int bn = blockIdx.x, bk = blockIdx.y;
  const int tx = threadIdx.x & 31, ty = threadIdx.x >> 5;
#pragma unroll
  for (int j = 0; j < 4; ++j)
    tile[ty + j * 8][tx] = W[(size_t)(bk * 32 + ty + j * 8) * 1024 + bn * 32 + tx];
  __syncthreads();
#pragma unroll
  for (int j = 0; j < 4; ++j)
    D[(size_t)(bn * 32 + ty + j * 8) * 1024 + bk * 32 + tx] = f2bf(tile[tx][ty + j * 8]);
}

// --- Wbt[b][n][k] = bf16( Wtt[n][k] * pk[b][k] * pq[b][k] ) ----------------
__global__ __launch_bounds__(256) void k_wbt(const u16* __restrict__ Wtt,
                                             const float* __restrict__ pk,
                                             const float* __restrict__ pq,
                                             u16* __restrict__ Wbt) {
  const int i = blockIdx.x * 256 + threadIdx.x;  // 1048576 threads
  const int k0 = (i & 127) * 8;
  const int n  = (i >> 7) & 1023;
  const int b  = i >> 17;
  bf16x8 wv = *reinterpret_cast<const bf16x8*>(&Wtt[n * 1024 + k0]);
  bf16x8 o;
#pragma unroll
  for (int j = 0; j < 8; ++j) {
    const float p = pk[b * 1024 + k0 + j] * pq[b * 1024 + k0 + j];
    o[j] = (short)f2bf(bf2f((u16)wv[j]) * p);
  }
  *reinterpret_cast<bf16x8*>(&Wbt[(size_t)b * 1048576 + (size_t)n * 1024 + k0]) = o;
}

// --- 256x128 GEMM: A via LDS (dbuf 64 KiB), B via L2->registers ------------
// 256 threads = 4 waves (2M x 2N); wave tile 128x64; BK=64; 16 K-tiles.
// Per tile: issue B(t+1)->regs, ds_read A halves + MFMA, barrier,
// stage A(t+2), vmcnt(8) [retires stage(t+1)+B(t+1)], barrier.
// EPI 0: bf16 out; block's 128 cols land wholly in C0 (ci<8) or C1.
// EPI 2: f32 out = acc + bias0[col] + bf2f(extra[row,col]); Bt per-batch.
template <int EPI>
__global__ __launch_bounds__(256, 2) void k_gemm(const u16* __restrict__ A,
                                                 const u16* __restrict__ Bt,
                                                 const float* __restrict__ bias0,
                                                 const float* __restrict__ bias1,
                                                 const u16* __restrict__ extra,
                                                 float* __restrict__ Cf,
                                                 u16* __restrict__ C0,
                                                 u16* __restrict__ C1,
                                                 int gcols) {
  __shared__ __align__(16) u16 lds[32768];  // 2 bufs x [256][64] bf16 = 64 KiB
  const int tid = threadIdx.x;
  const int w = tid >> 6, lane = tid & 63;
  const int wm = w >> 1, wn = w & 1;

  // chunked XCD swizzle (nwg % 8 == 0)
  const int nwg = gridDim.x;
  const int swz = (blockIdx.x & 7) * (nwg >> 3) + (blockIdx.x >> 3);
  const int ci = swz % gcols, ri = swz / gcols;
  const int row0 = ri * 256, col0 = ci * 128;

  const int lr15 = lane & 15, lhi = lane >> 4, lx = lane & 7;

  // A staging: dest row = p*32 + (tid>>3), slot = tid&7; source pre-swizzled
  // so physical slot s holds logical slot s ^ (row&7).
  const int ls8 = ((tid & 7) ^ ((tid >> 3) & 7)) * 8;
  const u16* gA = A + (size_t)(row0 + (tid >> 3)) * 1024 + ls8;

  // B per-lane fragment base: row (col) = col0 + wn*64 + lr15, k-off lhi*8
  const u16* gBf;
  if (EPI == 2) {
    gBf = Bt + (size_t)(row0 >> 12) * 1048576 +
          (size_t)(col0 + wn * 64 + lr15) * 1024 + lhi * 8;
  } else {
    gBf = Bt + (size_t)(col0 + wn * 64 + lr15) * 1024 + lhi * 8;
  }

  auto stageA = [&](int buf, int kt) {
#pragma unroll
    for (int p = 0; p < 8; ++p) {
      const u16* src = gA + (size_t)(p * 32) * 1024 + kt;
      u16* dst = (u16*)((char*)lds + buf * 32768 + p * 4096 + tid * 16);
      __builtin_amdgcn_global_load_lds(
          (const __attribute__((address_space(1))) void*)src,
          (__attribute__((address_space(3))) void*)dst, 16, 0, 0);
    }
  };

  f32x4 acc[8][4] = {};
  bf16x8 Af[4][2], Bc[4][2], Bn[4][2];

#define RD_A(ahalf)                                                            \
  _Pragma("unroll") for (int mi = 0; mi < 4; ++mi)                             \
  _Pragma("unroll") for (int ks = 0; ks < 2; ++ks)                             \
    Af[mi][ks] = *reinterpret_cast<const bf16x8*>(                             \
        &bA[(wm * 128 + (ahalf) * 64 + mi * 16 + lr15) * 64 +                  \
            (((ks << 2) | lhi) ^ lx) * 8]);
#define MFMA_HALF(BB, mo)                                                      \
  _Pragma("unroll") for (int mi = 0; mi < 4; ++mi)                             \
  _Pragma("unroll") for (int ni = 0; ni < 4; ++ni)                             \
  _Pragma("unroll") for (int ks = 0; ks < 2; ++ks)                             \
    acc[(mo) + mi][ni] = __builtin_amdgcn_mfma_f32_16x16x32_bf16(              \
        Af[mi][ks], BB[ni][ks], acc[(mo) + mi][ni], 0, 0, 0);
#define LOAD_B(BB, kt)                                                         \
  _Pragma("unroll") for (int ni = 0; ni < 4; ++ni)                             \
  _Pragma("unroll") for (int ks = 0; ks < 2; ++ks)                             \
    BB[ni][ks] = gload16(gBf + (size_t)ni * 16 * 1024 + (kt) + ks * 32);

  // prologue. FIFO: [stage0:8, B0:8, stage1:8] -> vmcnt(8) leaves [stage1:8]
  stageA(0, 0);
  LOAD_B(Bc, 0);
  stageA(1, 64);
  VMCNT8_;
  SBAR_;
  SB0_;

  // tile body: BC = current-tile B regs, BN = next-tile B regs
#define TILE(t, BC, BN)                                                        \
  {                                                                            \
    const u16* bA = &lds[cur * 16384];                                         \
    if ((t) < 15) { LOAD_B(BN, ((t) + 1) * 64); }                              \
    SB0_;                                                                      \
    RD_A(0);                                                                   \
    LGKM0_;                                                                    \
    __builtin_amdgcn_s_setprio(1);                                             \
    MFMA_HALF(BC, 0);                                                          \
    __builtin_amdgcn_s_setprio(0);                                             \
    SB0_;                                                                      \
    RD_A(1);                                                                   \
    LGKM0_;                                                                    \
    __builtin_amdgcn_s_setprio(1);                                             \
    MFMA_HALF(BC, 4);                                                          \
    __builtin_amdgcn_s_setprio(0);                                             \
    SBAR_;  /* all waves done reading buf[cur] */                              \
    SB0_;                                                                      \
    if ((t) < 14) { stageA(cur, ((t) + 2) * 64); }                             \
    if ((t) < 14) { VMCNT8_; } else if ((t) == 14) { VMCNT0_; }                \
    SBAR_;  /* buf[cur^1] (tile t+1) fully staged across waves */              \
    cur ^= 1;                                                                  \
  }

  int cur = 0;
  for (int t2 = 0; t2 < 8; ++t2) {
    TILE(2 * t2, Bc, Bn);
    TILE(2 * t2 + 1, Bn, Bc);
  }
#undef TILE
#undef RD_A
#undef MFMA_HALF
#undef LOAD_B

  // ---- epilogue: LDS-staged coalesced stores ----
  // acc: col = col0 + wn*64 + n*16 + lr15 (0..127 local);
  //      row = row0 + wm*128 + m*16 + lhi*4 + j (0..255 local).
  if constexpr (EPI == 0) {
    // whole 256x128 bf16 tile = 64 KiB
    u16* cl = (u16*)lds;
    const bool lo = (ci < (gcols >> 1));
    const float* bias = lo ? bias0 : bias1;
    u16* dst = lo ? C0 : C1;
    const int colloc0 = col0 - (lo ? 0 : 1024);
#pragma unroll
    for (int n = 0; n < 4; ++n) {
      const int cc = wn * 64 + n * 16 + lr15;
      const float bv = bias[colloc0 + cc];
#pragma unroll
      for (int m = 0; m < 8; ++m) {
        const int rb = wm * 128 + m * 16 + lhi * 4;
#pragma unroll
        for (int j = 0; j < 4; ++j) {
          const int r = rb + j;
          cl[r * 128 + (cc ^ ((r & 12) << 2))] = f2bf(acc[m][n][j] + bv);
        }
      }
    }
    __syncthreads();
#pragma unroll
    for (int pass = 0; pass < 16; ++pass) {
      const int idx = pass * 256 + tid;
      const int r = idx >> 4, g = idx & 15;  // 256 rows x 16 groups of 8 u16
      bf16x8 v = *reinterpret_cast<const bf16x8*>(
          &cl[r * 128 + ((g * 8) ^ ((r & 12) << 2))]);
      *reinterpret_cast<bf16x8*>(
          &dst[(size_t)(row0 + r) * 1024 + colloc0 + g * 8]) = v;
    }
  } else {
    // f32: two half-tiles of 128 rows x 128 cols = 64 KiB each
    float* clf = (float*)lds;
#pragma unroll
    for (int half = 0; half < 2; ++half) {
      __syncthreads();
      if (wm == half) {
#pragma unroll
        for (int n = 0; n < 4; ++n) {
          const int cc = wn * 64 + n * 16 + lr15;
#pragma unroll
          for (int m = 0; m < 8; ++m) {
            const int rb = m * 16 + lhi * 4;
#pragma unroll
            for (int j = 0; j < 4; ++j) {
              const int r = rb + j;
              clf[r * 128 + (cc ^ ((r & 12) << 2))] = acc[m][n][j];
            }
          }
        }
      }
      __syncthreads();
#pragma unroll
      for (int pass = 0; pass < 16; ++pass) {
        const int idx = pass * 256 + tid;
        const int r = idx >> 5, g = idx & 31;  // 128 rows x 32 groups of f32x4
        f32x4 v = *reinterpret_cast<const f32x4*>(
            &clf[r * 128 + ((g * 4) ^ ((r & 12) << 2))]);
        const int grow = row0 + half * 128 + r;
        const int gcol = col0 + g * 4;
        ushort4 e = *reinterpret_cast<const ushort4*>(
            &extra[(size_t)grow * 1024 + gcol]);
        float4 o;
        o.x = v[0] + bias0[gcol + 0] + bf2f(e.x);
        o.y = v[1] + bias0[gcol + 1] + bf2f(e.y);
        o.z = v[2] + bias0[gcol + 2] + bf2f(e.z);
        o.w = v[3] + bias0[gcol + 3] + bf2f(e.w);
        *reinterpret_cast<float4*>(&Cf[(size_t)grow * 1024 + gcol]) = o;
      }
    }
  }
}

// --- score[b,h,s] = (X[b,s,:].Weff[:,h] + bias[h])*scale + mask[b,s] -------
template <int HAS_PQ>
__global__ __launch_bounds__(256) void k_score(const u16* __restrict__ X,
                                               const float* __restrict__ Wa,
                                               const float* __restrict__ bias,
                                               const float* __restrict__ mask,
                                               const float* __restrict__ pq,
                                               float* __restrict__ score,
                                               float scale) {
  __shared__ float waT[16][1024];  // [h][d]
  const int b = blockIdx.y;
  for (int t = threadIdx.x; t < 16384; t += 256) {
    const int d = t >> 4, h = t & 15;
    float wv = Wa[t];
    if (HAS_PQ) wv *= pq[b * 1024 + d];
    waT[h][d] = wv;
  }
  __syncthreads();
  const int w = threadIdx.x >> 6, l = threadIdx.x & 63;
  for (int g = blockIdx.x * 4 + w; g < 1024; g += gridDim.x * 4) {
    const size_t r0 = (size_t)b * 4096 + g * 4;
    float cur[64];  // idx = rr*16 + h
#pragma unroll
    for (int i = 0; i < 64; ++i) cur[i] = 0.f;
    for (int i = 0; i < 8; ++i) {
      const int d = i * 128 + l * 2;
      float xv[4][2];
#pragma unroll
      for (int rr = 0; rr < 4; ++rr) {
        ushort2 xq = *reinterpret_cast<const ushort2*>(&X[(r0 + rr) * 1024 + d]);
        xv[rr][0] = bf2f(xq.x); xv[rr][1] = bf2f(xq.y);
      }
#pragma unroll
      for (int h = 0; h < 16; ++h) {
        float2 wv = *reinterpret_cast<const float2*>(&waT[h][d]);
#pragma unroll
        for (int rr = 0; rr < 4; ++rr)
          cur[rr * 16 + h] += xv[rr][0] * wv.x + xv[rr][1] * wv.y;
      }
    }
#pragma unroll
    for (int s = 0; s < 6; ++s) {
      const int m = 1 << s;
      const int bit = (l >> s) & 1;
#pragma unroll
      for (int j = 0; j < (32 >> s); ++j) {
        const float mine = bit ? cur[2 * j + 1] : cur[2 * j];
        const float other = bit ? cur[2 * j] : cur[2 * j + 1];
        cur[j] = mine + __shfl_xor(other, m, 64);
      }
    }
    const int rr = l >> 4, h = l & 15;
    const int si = g * 4 + rr;
    score[((size_t)b * 16 + h) * 4096 + si] =
        (cur[0] + bias[h]) * scale + mask[b * 4096 + si];
  }
}

// --- softmax over S (in place), one block per (b,h) row --------------------
__global__ __launch_bounds__(256) void k_softmax(float* __restrict__ sc) {
  __shared__ float red[8];
  float* p = sc + (size_t)blockIdx.x * 4096;
  const int t = threadIdx.x, w = t >> 6, l = t & 63;
  float v[16];
  float mx = -3.0e38f;
#pragma unroll
  for (int i = 0; i < 16; ++i) { v[i] = p[t + i * 256]; mx = fmaxf(mx, v[i]); }
#pragma unroll
  for (int m = 1; m < 64; m <<= 1) mx = fmaxf(mx, __shfl_xor(mx, m, 64));
  if (l == 0) red[w] = mx;
  __syncthreads();
  mx = fmaxf(fmaxf(red[0], red[1]), fmaxf(red[2], red[3]));
  float sum = 0.f;
#pragma unroll
  for (int i = 0; i < 16; ++i) { v[i] = __expf(v[i] - mx); sum += v[i]; }
#pragma unroll
  for (int m = 1; m < 64; m <<= 1) sum += __shfl_xor(sum, m, 64);
  if (l == 0) red[4 + w] = sum;
  __syncthreads();
  const float inv = 1.f / (red[4] + red[5] + red[6] + red[7]);
#pragma unroll
  for (int i = 0; i < 16; ++i) p[t + i * 256] = v[i] * inv;
}

// --- pooled[b,d] = sum_s w[b, d>>6, s] * X[b,s,d]  (bf16 X, atomics) -------
__global__ __launch_bounds__(256) void k_pool(const float* __restrict__ wgt,
                                              const u16* __restrict__ X,
                                              float* __restrict__ pooled) {
  __shared__ float wl[16][132];
  const int b = blockIdx.x >> 5, c = blockIdx.x & 31;
  const int s0 = c * 128;
  for (int t = threadIdx.x; t < 2048; t += 256) {
    const int h = t >> 7, si = t & 127;
    wl[h][si] = wgt[((size_t)b * 16 + h) * 4096 + s0 + si];
  }
  __syncthreads();
  const int d0 = threadIdx.x * 4, h = threadIdx.x >> 4;
  float a0 = 0, a1 = 0, a2 = 0, a3 = 0;
  for (int si = 0; si < 128; ++si) {
    const float wv = wl[h][si];
    const size_t base = ((size_t)b * 4096 + s0 + si) * 1024 + d0;
    ushort4 xq = *reinterpret_cast<const ushort4*>(X + base);
    a0 += wv * bf2f(xq.x); a1 += wv * bf2f(xq.y);
    a2 += wv * bf2f(xq.z); a3 += wv * bf2f(xq.w);
  }
  atomicAdd(&pooled[b * 1024 + d0 + 0], a0);
  atomicAdd(&pooled[b * 1024 + d0 + 1], a1);
  atomicAdd(&pooled[b * 1024 + d0 + 2], a2);
  atomicAdd(&pooled[b * 1024 + d0 + 3], a3);
}

// ---------------------------------------------------------------------------
extern "C" void kernel_launch(void* const* d_in, const int* in_sizes, int n_in,
                              void* d_out, int out_size, void* d_ws, size_t ws_size,
                              hipStream_t stream) {
  (void)in_sizes; (void)n_in; (void)out_size; (void)ws_size;
  const float* x    = (const float*)d_in[0];
  const float* mask = (const float*)d_in[1];
  const float* Wq   = (const float*)d_in[2];
  const float* bq   = (const float*)d_in[3];
  const float* Wqa  = (const float*)d_in[4];
  const float* bqa  = (const float*)d_in[5];
  const float* Wk   = (const float*)d_in[6];
  const float* bk   = (const float*)d_in[7];
  const float* Wka  = (const float*)d_in[8];
  const float* bka  = (const float*)d_in[9];
  const float* Wt   = (const float*)d_in[10];
  const float* bt   = (const float*)d_in[11];
  float* out = (float*)d_out;
  char* ws = (char*)d_ws;

  size_t off = 0;
  auto take = [&](size_t b) { char* p = ws + off; off += (b + 255) & ~(size_t)255; return p; };
  u16*   xb    = (u16*)  take(67108864);   // x bf16
  u16*   qb    = (u16*)  take(67108864);   // q bf16
  u16*   kb    = (u16*)  take(67108864);   // k bf16
  u16*   Wqkt  = (u16*)  take(4194304);    // [Wq^T ; Wk^T] (2048 x 1024) bf16
  u16*   Wtt   = (u16*)  take(2097152);    // Wt^T bf16
  u16*   Wbt   = (u16*)  take(16777216);   // per-batch out weights (8x1024x1024)
  float* sc    = (float*)take(2097152);    // (B,H,S) scores
  float* pq    = (float*)take(32768);      // pooled_q (B,1024)
  float* pk    = (float*)take(32768);      // raw pooled_k (B,1024)

  // prep
  k_cvt<<<2048, 256, 0, stream>>>(x, xb, 8388608);
  k_transw<<<dim3(32, 32, 3), 256, 0, stream>>>(Wq, Wk, Wt, Wqkt, Wtt);

  // fused q,k = x @ [Wq|Wk] + [bq|bk]   (128 row-tiles x 16 col-tiles)
  k_gemm<0><<<2048, 256, 0, stream>>>(xb, Wqkt, bq, bk, nullptr, nullptr, qb, kb, 16);

  // q path
  k_score<0><<<dim3(128, 8), 256, 0, stream>>>(qb, Wqa, bqa, mask, nullptr, sc, 0.125f);
  k_softmax<<<128, 256, 0, stream>>>(sc);
  hipMemsetAsync(pq, 0, 32768, stream);
  k_pool<<<256, 256, 0, stream>>>(sc, qb, pq);

  // k path (mixed_qk factored out)
  k_score<1><<<dim3(128, 8), 256, 0, stream>>>(kb, Wka, bka, mask, pq, sc, 0.125f);
  k_softmax<<<128, 256, 0, stream>>>(sc);
  hipMemsetAsync(pk, 0, 32768, stream);
  k_pool<<<256, 256, 0, stream>>>(sc, kb, pk);

  // out = (q .* pk .* pq) @ Wt + bt + q  ==  q @ W_b + bt + q
  k_wbt<<<4096, 256, 0, stream>>>(Wtt, pk, pq, Wbt);
  k_gemm<2><<<1024, 256, 0, stream>>>(qb, Wbt, bt, nullptr, qb, out, nullptr, nullptr, 8);
}

// Round 9
// 545.505 us; speedup vs baseline: 1.0776x; 1.0776x over previous
//
#include <hip/hip_runtime.h>

// ---------------------------------------------------------------------------
// FastSelfAttention on MI355X (gfx950), round 9.
// B=8, S=4096, D=1024, H=16, DH=64.
// R9: R8's race fixed — no cross-tile LDS pre-reads; all reads of a tile
// issue after the tile's buffer is vmcnt+barrier-proven. No inline lgkm
// fences (compiler counted waits overlap LDS service with MFMA drain).
// 2 barriers + 1 counted vmcnt per tile. Softmax-free pipeline kept:
// score computes running max, pool applies exp on the fly, 1/sum folded
// into k_score<1> / k_wbt. 10 launches.
// ---------------------------------------------------------------------------

typedef unsigned short u16;
typedef float f32x4 __attribute__((ext_vector_type(4)));
typedef short bf16x8 __attribute__((ext_vector_type(8)));

#define DEV __device__ __forceinline__

DEV u16 f2bf(float f) {
  union { float f; unsigned u; } c; c.f = f;
  return (u16)((c.u + 0x7FFFu + ((c.u >> 16) & 1u)) >> 16);
}
DEV float bf2f(u16 h) {
  union { unsigned u; float f; } c; c.u = ((unsigned)h) << 16;
  return c.f;
}
// monotonic float<->uint key (for atomicMax on float values incl. negatives)
DEV unsigned fkey(float f) {
  unsigned u = __float_as_uint(f);
  return u ^ (unsigned)(((int)u >> 31) | 0x80000000);
}
DEV float unkey(unsigned k) {
  unsigned u = (k & 0x80000000u) ? (k ^ 0x80000000u) : ~k;
  return __uint_as_float(u);
}

#define SBAR_  __builtin_amdgcn_s_barrier()
#define SB0_   __builtin_amdgcn_sched_barrier(0)
#define VMCNT8_ do { asm volatile("s_waitcnt vmcnt(8)" ::: "memory"); SB0_; } while (0)
#define VMCNT0_ do { asm volatile("s_waitcnt vmcnt(0)" ::: "memory"); SB0_; } while (0)

// --- f32 -> bf16 bulk convert ----------------------------------------------
__global__ __launch_bounds__(256) void k_cvt(const float* __restrict__ in,
                                             u16* __restrict__ out, int n4) {
  int i = blockIdx.x * 256 + threadIdx.x;
  const int stride = gridDim.x * 256;
  for (; i < n4; i += stride) {
    float4 v = reinterpret_cast<const float4*>(in)[i];
    ushort4 o;
    o.x = f2bf(v.x); o.y = f2bf(v.y); o.z = f2bf(v.z); o.w = f2bf(v.w);
    reinterpret_cast<ushort4*>(out)[i] = o;
  }
}

// --- W (K,N) f32 -> W^T (N,K) bf16, 3 weights in one launch (z selects) ----
__global__ __launch_bounds__(256) void k_transw(const float* __restrict__ Wq,
                                                const float* __restrict__ Wk,
                                                const float* __restrict__ Wt,
                                                u16* __restrict__ Wqkt,
                                                u16* __restrict__ Wtt) {
  __shared__ float tile[32][33];
  const int z = blockIdx.z;
  const float* W = (z == 0) ? Wq : (z == 1) ? Wk : Wt;
  u16* D = (z == 0) ? Wqkt : (z == 1) ? (Wqkt + 1024 * 1024) : Wtt;
  const int bn = blockIdx.x, bk = blockIdx.y;
  const int tx = threadIdx.x & 31, ty = threadIdx.x >> 5;
#pragma unroll
  for (int j = 0; j < 4; ++j)
    tile[ty + j * 8][tx] = W[(size_t)(bk * 32 + ty + j * 8) * 1024 + bn * 32 + tx];
  __syncthreads();
#pragma unroll
  for (int j = 0; j < 4; ++j)
    D[(size_t)(bn * 32 + ty + j * 8) * 1024 + bk * 32 + tx] = f2bf(tile[tx][ty + j * 8]);
}

// --- Wbt[b][n][k] = bf16( Wtt[n][k] * pkr*pqr / (sumk*sumq) ) --------------
__global__ __launch_bounds__(256) void k_wbt(const u16* __restrict__ Wtt,
                                             const float* __restrict__ pkr,
                                             const float* __restrict__ pqr,
                                             const float* __restrict__ sumk,
                                             const float* __restrict__ sumq,
                                             u16* __restrict__ Wbt) {
  const int i = blockIdx.x * 256 + threadIdx.x;  // 1048576 threads
  const int k0 = (i & 127) * 8;
  const int n  = (i >> 7) & 1023;
  const int b  = i >> 17;
  const int hh = k0 >> 6;  // head of k-dim (8 elems stay in one head; DH=64)
  const float inv = 1.0f / (sumk[b * 16 + hh] * sumq[b * 16 + hh]);
  bf16x8 wv = *reinterpret_cast<const bf16x8*>(&Wtt[n * 1024 + k0]);
  bf16x8 o;
#pragma unroll
  for (int j = 0; j < 8; ++j) {
    const float p = pkr[b * 1024 + k0 + j] * pqr[b * 1024 + k0 + j] * inv;
    o[j] = (short)f2bf(bf2f((u16)wv[j]) * p);
  }
  *reinterpret_cast<bf16x8*>(&Wbt[(size_t)b * 1048576 + (size_t)n * 1024 + k0]) = o;
}

// --- 256x256 GEMM, unfenced counted-lgkm pipeline, LDS-staged epilogue -----
// C = A(Mx1024) x Bt(Nx1024)^T. 512 threads = 8 waves (2M x 4N), BK=64,
// double-buffered 128 KiB XOR-swizzled LDS. Per tile: all 24 ds_reads issue
// inside the tile (no fences -> compiler counted lgkm waits), 4 MFMA
// quadrants, barrier, stage t+2, vmcnt(8), barrier.
// EPI 0: bf16 out; block's cols land wholly in C0 (ci<gcols/2) or C1.
// EPI 2: f32 out = acc + bias0[col] + bf2f(extra[row,col]); Bt per-batch.
template <int EPI>
__global__ __launch_bounds__(512, 2) void k_gemm8(const u16* __restrict__ A,
                                                  const u16* __restrict__ Bt,
                                                  const float* __restrict__ bias0,
                                                  const float* __restrict__ bias1,
                                                  const u16* __restrict__ extra,
                                                  float* __restrict__ Cf,
                                                  u16* __restrict__ C0,
                                                  u16* __restrict__ C1,
                                                  int gcols) {
  __shared__ __align__(16) u16 lds[2 * 32768];  // [buf][A|B][256][64]
  const int tid = threadIdx.x;
  const int w = tid >> 6, lane = tid & 63;
  const int wm = w >> 2, wn = w & 3;

  // chunked XCD swizzle (nwg % 8 == 0)
  const int nwg = gridDim.x;
  const int swz = (blockIdx.x & 7) * (nwg >> 3) + (blockIdx.x >> 3);
  const int ci = swz % gcols, ri = swz / gcols;
  const int row0 = ri * 256, col0 = ci * 256;

  // staging: dest row = half*128 + p*64 + (tid>>3), slot = tid&7; source
  // pre-swizzled so physical slot s holds logical slot s ^ (row&7).
  const int sr = tid >> 3;
  const int ls8 = ((tid & 7) ^ (sr & 7)) * 8;
  const u16* gA = A + (size_t)(row0 + sr) * 1024 + ls8;
  const u16* gB;
  if (EPI == 2) {
    gB = Bt + (size_t)(row0 >> 12) * 1048576 + (size_t)(col0 + sr) * 1024 + ls8;
  } else {
    gB = Bt + (size_t)(col0 + sr) * 1024 + ls8;
  }

  auto stage = [&](int buf, int mat, int half, int kt, const u16* g) {
#pragma unroll
    for (int p = 0; p < 2; ++p) {
      const u16* src = g + (size_t)(half * 128 + p * 64) * 1024 + kt;
      u16* dst = (u16*)&lds[buf * 32768 + mat * 16384 + half * 8192 + p * 4096 + w * 512];
      __builtin_amdgcn_global_load_lds(
          (const __attribute__((address_space(1))) void*)src,
          (__attribute__((address_space(3))) void*)dst, 16, 0, 0);
    }
  };

  f32x4 acc[8][4] = {};

  // prologue: tile 0 -> buf0, tile 1 -> buf1
#pragma unroll
  for (int tt = 0; tt < 2; ++tt) {
    stage(tt, 0, 0, tt * 64, gA);
    stage(tt, 0, 1, tt * 64, gA);
    stage(tt, 1, 0, tt * 64, gB);
    stage(tt, 1, 1, tt * 64, gB);
  }
  VMCNT8_;  // tile0 landed
  SBAR_;
  SB0_;

  const int lr15 = lane & 15, lhi = lane >> 4, lx = lane & 7;
  bf16x8 A0[4][2], A1[4][2], B0[2][2], B1[2][2];

#define RD_Ah(dst, base, half)                                                 \
  _Pragma("unroll") for (int mi = 0; mi < 4; ++mi)                             \
  _Pragma("unroll") for (int ks = 0; ks < 2; ++ks)                             \
    dst[mi][ks] = *reinterpret_cast<const bf16x8*>(                            \
        &(base)[(wm * 128 + (half) * 64 + mi * 16 + lr15) * 64 +               \
                (((ks << 2) | lhi) ^ lx) * 8]);
#define RD_Bh(dst, base, half)                                                 \
  _Pragma("unroll") for (int ni = 0; ni < 2; ++ni)                             \
  _Pragma("unroll") for (int ks = 0; ks < 2; ++ks)                             \
    dst[ni][ks] = *reinterpret_cast<const bf16x8*>(                            \
        &(base)[(wn * 64 + (half) * 32 + ni * 16 + lr15) * 64 +                \
                (((ks << 2) | lhi) ^ lx) * 8]);
#define MFMA_Q(ar, br, mo, no)                                                 \
  _Pragma("unroll") for (int mi = 0; mi < 4; ++mi)                             \
  _Pragma("unroll") for (int ni = 0; ni < 2; ++ni)                             \
  _Pragma("unroll") for (int ks = 0; ks < 2; ++ks)                             \
    acc[(mo) + mi][(no) + ni] = __builtin_amdgcn_mfma_f32_16x16x32_bf16(       \
        ar[mi][ks], br[ni][ks], acc[(mo) + mi][(no) + ni], 0, 0, 0);

  int cur = 0;
  for (int t = 0; t < 16; ++t) {
    const u16* bA = &lds[cur * 32768];
    const u16* bB = bA + 16384;
    // issue reads (no fences; compiler inserts counted lgkm waits per MFMA)
    RD_Ah(A0, bA, 0);
    RD_Bh(B0, bB, 0);
    RD_Bh(B1, bB, 1);
    __builtin_amdgcn_s_setprio(1);
    MFMA_Q(A0, B0, 0, 0);
    __builtin_amdgcn_s_setprio(0);
    RD_Ah(A1, bA, 1);
    __builtin_amdgcn_s_setprio(1);
    MFMA_Q(A0, B1, 0, 2);
    MFMA_Q(A1, B1, 4, 2);
    MFMA_Q(A1, B0, 4, 0);
    __builtin_amdgcn_s_setprio(0);
    SBAR_;  // all waves' reads of buf[cur] retired (consumed by MFMAs above)
    SB0_;
    if (t < 14) {
      stage(cur, 1, 0, (t + 2) * 64, gB);
      stage(cur, 1, 1, (t + 2) * 64, gB);
      stage(cur, 0, 0, (t + 2) * 64, gA);
      stage(cur, 0, 1, (t + 2) * 64, gA);
      VMCNT8_;  // retire tile t+1's stages (issued last tile)
    } else if (t == 14) {
      VMCNT0_;
    }
    SBAR_;  // buf[cur^1] (tile t+1) fully staged & visible across waves
    cur ^= 1;
  }
#undef RD_Ah
#undef RD_Bh
#undef MFMA_Q

  // ---- epilogue: LDS-staged coalesced stores (R4) ----
  if constexpr (EPI == 0) {
    u16* cl = (u16*)lds;
    const bool lo = (ci < (gcols >> 1));
    const float* bias = lo ? bias0 : bias1;
    u16* dst = lo ? C0 : C1;
    const int colloc0 = col0 - (lo ? 0 : 1024);
#pragma unroll
    for (int n = 0; n < 4; ++n) {
      const int cc = wn * 64 + n * 16 + lr15;
      const float bv = bias[colloc0 + cc];
#pragma unroll
      for (int m = 0; m < 8; ++m) {
        const int rb = wm * 128 + m * 16 + lhi * 4;
#pragma unroll
        for (int j = 0; j < 4; ++j) {
          const int r = rb + j;
          cl[r * 256 + (cc ^ ((r & 12) << 2))] = f2bf(acc[m][n][j] + bv);
        }
      }
    }
    __syncthreads();
#pragma unroll
    for (int pass = 0; pass < 16; ++pass) {
      const int idx = pass * 512 + tid;
      const int r = idx >> 5, g = idx & 31;
      bf16x8 v = *reinterpret_cast<const bf16x8*>(
          &cl[r * 256 + ((g * 8) ^ ((r & 12) << 2))]);
      *reinterpret_cast<bf16x8*>(
          &dst[(size_t)(row0 + r) * 1024 + colloc0 + g * 8]) = v;
    }
  } else {
    float* clf = (float*)lds;
#pragma unroll
    for (int half = 0; half < 2; ++half) {
      __syncthreads();
      if (wm == half) {
#pragma unroll
        for (int n = 0; n < 4; ++n) {
          const int cc = wn * 64 + n * 16 + lr15;
#pragma unroll
          for (int m = 0; m < 8; ++m) {
            const int rb = m * 16 + lhi * 4;
#pragma unroll
            for (int j = 0; j < 4; ++j) {
              const int r = rb + j;
              clf[r * 256 + (cc ^ ((r & 12) << 2))] = acc[m][n][j];
            }
          }
        }
      }
      __syncthreads();
#pragma unroll
      for (int pass = 0; pass < 16; ++pass) {
        const int idx = pass * 512 + tid;
        const int r = idx >> 6, g = idx & 63;
        f32x4 v = *reinterpret_cast<const f32x4*>(
            &clf[r * 256 + ((g * 4) ^ ((r & 12) << 2))]);
        const int grow = row0 + half * 128 + r;
        const int gcol = col0 + g * 4;
        ushort4 e = *reinterpret_cast<const ushort4*>(
            &extra[(size_t)grow * 1024 + gcol]);
        float4 o;
        o.x = v[0] + bias0[gcol + 0] + bf2f(e.x);
        o.y = v[1] + bias0[gcol + 1] + bf2f(e.y);
        o.z = v[2] + bias0[gcol + 2] + bf2f(e.z);
        o.w = v[3] + bias0[gcol + 3] + bf2f(e.w);
        *reinterpret_cast<float4*>(&Cf[(size_t)grow * 1024 + gcol]) = o;
      }
    }
  }
}

// --- score[b,h,s] = (X.Weff[:,h] + bias[h])*scale + mask; + running max ----
// HAS_PQ: Weff[d,h] = Wa[d,h] * pqr[b,d] / sumq[b, d>>6].
template <int HAS_PQ>
__global__ __launch_bounds__(256) void k_score(const u16* __restrict__ X,
                                               const float* __restrict__ Wa,
                                               const float* __restrict__ bias,
                                               const float* __restrict__ mask,
                                               const float* __restrict__ pqr,
                                               const float* __restrict__ sumq,
                                               float* __restrict__ score,
                                               unsigned* __restrict__ maxkey,
                                               float scale) {
  __shared__ float waT[16][1024];  // [h][d]
  __shared__ unsigned bmx[4][16];
  __shared__ float invs[16];
  const int b = blockIdx.y;
  if (HAS_PQ && threadIdx.x < 16) invs[threadIdx.x] = 1.0f / sumq[b * 16 + threadIdx.x];
  if (HAS_PQ) __syncthreads();
  for (int t = threadIdx.x; t < 16384; t += 256) {
    const int d = t >> 4, h = t & 15;
    float wv = Wa[t];
    if (HAS_PQ) wv *= pqr[b * 1024 + d] * invs[d >> 6];
    waT[h][d] = wv;
  }
  __syncthreads();
  const int w = threadIdx.x >> 6, l = threadIdx.x & 63;
  float rm = -3.0e38f;  // running max for this lane's h
  for (int g = blockIdx.x * 4 + w; g < 1024; g += gridDim.x * 4) {
    const size_t r0 = (size_t)b * 4096 + g * 4;
    float cur[64];  // idx = rr*16 + h
#pragma unroll
    for (int i = 0; i < 64; ++i) cur[i] = 0.f;
    for (int i = 0; i < 8; ++i) {
      const int d = i * 128 + l * 2;
      float xv[4][2];
#pragma unroll
      for (int rr = 0; rr < 4; ++rr) {
        ushort2 xq = *reinterpret_cast<const ushort2*>(&X[(r0 + rr) * 1024 + d]);
        xv[rr][0] = bf2f(xq.x); xv[rr][1] = bf2f(xq.y);
      }
#pragma unroll
      for (int h = 0; h < 16; ++h) {
        float2 wv = *reinterpret_cast<const float2*>(&waT[h][d]);
#pragma unroll
        for (int rr = 0; rr < 4; ++rr)
          cur[rr * 16 + h] += xv[rr][0] * wv.x + xv[rr][1] * wv.y;
      }
    }
#pragma unroll
    for (int s = 0; s < 6; ++s) {
      const int m = 1 << s;
      const int bit = (l >> s) & 1;
#pragma unroll
      for (int j = 0; j < (32 >> s); ++j) {
        const float mine = bit ? cur[2 * j + 1] : cur[2 * j];
        const float other = bit ? cur[2 * j] : cur[2 * j + 1];
        cur[j] = mine + __shfl_xor(other, m, 64);
      }
    }
    const int rr = l >> 4, h = l & 15;
    const int si = g * 4 + rr;
    const float v = (cur[0] + bias[h]) * scale + mask[b * 4096 + si];
    score[((size_t)b * 16 + h) * 4096 + si] = v;
    rm = fmaxf(rm, v);
  }
  // reduce rm over the 4 rr-lane groups (same h at l, l^16, l^32)
  rm = fmaxf(rm, __shfl_xor(rm, 16, 64));
  rm = fmaxf(rm, __shfl_xor(rm, 32, 64));
  if (l < 16) bmx[w][l] = fkey(rm);
  __syncthreads();
  if (threadIdx.x < 16) {
    unsigned k = bmx[0][threadIdx.x];
    k = max(k, bmx[1][threadIdx.x]);
    k = max(k, bmx[2][threadIdx.x]);
    k = max(k, bmx[3][threadIdx.x]);
    atomicMax(&maxkey[b * 16 + threadIdx.x], k);
  }
}

// --- pool: w = exp(score-max); pooled_raw[b,d] += sum_s w*X; sum[b,h] += w --
__global__ __launch_bounds__(256) void k_pool(const float* __restrict__ score,
                                              const unsigned* __restrict__ maxkey,
                                              const u16* __restrict__ X,
                                              float* __restrict__ pooled,
                                              float* __restrict__ sumexp) {
  __shared__ float wl[16][132];
  const int b = blockIdx.x >> 5, c = blockIdx.x & 31;
  const int s0 = c * 128;
  for (int t = threadIdx.x; t < 2048; t += 256) {
    const int h = t >> 7, si = t & 127;
    const float mx = unkey(maxkey[b * 16 + h]);
    wl[h][si] = __expf(score[((size_t)b * 16 + h) * 4096 + s0 + si] - mx);
  }
  __syncthreads();
  // block-partial sumexp: thread t: h=t>>4, part=t&15 sums 8 elems
  {
    const int h = threadIdx.x >> 4, part = threadIdx.x & 15;
    float s = 0.f;
#pragma unroll
    for (int j = 0; j < 8; ++j) s += wl[h][part * 8 + j];
#pragma unroll
    for (int m = 1; m < 16; m <<= 1) s += __shfl_xor(s, m, 64);
    if (part == 0) atomicAdd(&sumexp[b * 16 + h], s);
  }
  const int d0 = threadIdx.x * 4, h = threadIdx.x >> 4;
  float a0 = 0, a1 = 0, a2 = 0, a3 = 0;
#pragma unroll 4
  for (int si = 0; si < 128; ++si) {
    const float wv = wl[h][si];
    const size_t base = ((size_t)b * 4096 + s0 + si) * 1024 + d0;
    ushort4 xq = *reinterpret_cast<const ushort4*>(X + base);
    a0 += wv * bf2f(xq.x); a1 += wv * bf2f(xq.y);
    a2 += wv * bf2f(xq.z); a3 += wv * bf2f(xq.w);
  }
  atomicAdd(&pooled[b * 1024 + d0 + 0], a0);
  atomicAdd(&pooled[b * 1024 + d0 + 1], a1);
  atomicAdd(&pooled[b * 1024 + d0 + 2], a2);
  atomicAdd(&pooled[b * 1024 + d0 + 3], a3);
}

// ---------------------------------------------------------------------------
extern "C" void kernel_launch(void* const* d_in, const int* in_sizes, int n_in,
                              void* d_out, int out_size, void* d_ws, size_t ws_size,
                              hipStream_t stream) {
  (void)in_sizes; (void)n_in; (void)out_size; (void)ws_size;
  const float* x    = (const float*)d_in[0];
  const float* mask = (const float*)d_in[1];
  const float* Wq   = (const float*)d_in[2];
  const float* bq   = (const float*)d_in[3];
  const float* Wqa  = (const float*)d_in[4];
  const float* bqa  = (const float*)d_in[5];
  const float* Wk   = (const float*)d_in[6];
  const float* bk   = (const float*)d_in[7];
  const float* Wka  = (const float*)d_in[8];
  const float* bka  = (const float*)d_in[9];
  const float* Wt   = (const float*)d_in[10];
  const float* bt   = (const float*)d_in[11];
  float* out = (float*)d_out;
  char* ws = (char*)d_ws;

  size_t off = 0;
  auto take = [&](size_t b) { char* p = ws + off; off += (b + 255) & ~(size_t)255; return p; };
  u16*   xb    = (u16*)  take(67108864);   // x bf16
  u16*   qb    = (u16*)  take(67108864);   // q bf16
  u16*   kb    = (u16*)  take(67108864);   // k bf16
  u16*   Wqkt  = (u16*)  take(4194304);    // [Wq^T ; Wk^T] (2048 x 1024) bf16
  u16*   Wtt   = (u16*)  take(2097152);    // Wt^T bf16
  u16*   Wbt   = (u16*)  take(16777216);   // per-batch out weights (8x1024x1024)
  float* sc    = (float*)take(2097152);    // (B,H,S) scores
  // contiguous zero-init block: pq_raw, pk_raw, sumq, sumk, maxq, maxk
  char*  nb    = take(68608);
  float*    pqr  = (float*)nb;               // 32768 B
  float*    pkr  = (float*)(nb + 32768);     // 32768 B
  float*    sumq = (float*)(nb + 65536);     // 512 B
  float*    sumk = (float*)(nb + 66048);     // 512 B
  unsigned* maxq = (unsigned*)(nb + 66560);  // 512 B
  unsigned* maxk = (unsigned*)(nb + 67072);  // 512 B

  // prep
  k_cvt<<<2048, 256, 0, stream>>>(x, xb, 8388608);
  k_transw<<<dim3(32, 32, 3), 256, 0, stream>>>(Wq, Wk, Wt, Wqkt, Wtt);
  hipMemsetAsync(nb, 0, 68608, stream);

  // fused q,k = x @ [Wq|Wk] + [bq|bk]
  k_gemm8<0><<<1024, 512, 0, stream>>>(xb, Wqkt, bq, bk, nullptr, nullptr, qb, kb, 8);

  // q path: score (+max), pool (+sumexp)
  k_score<0><<<dim3(128, 8), 256, 0, stream>>>(qb, Wqa, bqa, mask, nullptr, nullptr,
                                               sc, maxq, 0.125f);
  k_pool<<<256, 256, 0, stream>>>(sc, maxq, qb, pqr, sumq);

  // k path (mixed_qk factored out; 1/sumq folded into Weff)
  k_score<1><<<dim3(128, 8), 256, 0, stream>>>(kb, Wka, bka, mask, pqr, sumq,
                                               sc, maxk, 0.125f);
  k_pool<<<256, 256, 0, stream>>>(sc, maxk, kb, pkr, sumk);

  // out = q @ W_b + bt + q, W_b = diag(pkr*pqr/(sumk*sumq)) @ Wt per batch
  k_wbt<<<4096, 256, 0, stream>>>(Wtt, pkr, pqr, sumk, sumq, Wbt);
  k_gemm8<2><<<512, 512, 0, stream>>>(qb, Wbt, bt, nullptr, qb, out, nullptr, nullptr, 4);
}

// Round 10
// 530.314 us; speedup vs baseline: 1.1084x; 1.0286x over previous
//
#include <hip/hip_runtime.h>

// ---------------------------------------------------------------------------
// FastSelfAttention on MI355X (gfx950), round 10.
// B=8, S=4096, D=1024, H=16, DH=64.
// R10: faithful m201 8-phase GEMM template: 8 phases / 2 K-tiles, one
// half-tile staged per phase (just-in-time, race-free by phase ordering),
// counted vmcnt(4) at P4/P8 only, lgkmcnt(8) throttle on 12-read phases,
// zero sched_barriers, setprio around MFMA clusters. Rest = R9 (passed).
// ---------------------------------------------------------------------------

typedef unsigned short u16;
typedef float f32x4 __attribute__((ext_vector_type(4)));
typedef short bf16x8 __attribute__((ext_vector_type(8)));

#define DEV __device__ __forceinline__

DEV u16 f2bf(float f) {
  union { float f; unsigned u; } c; c.f = f;
  return (u16)((c.u + 0x7FFFu + ((c.u >> 16) & 1u)) >> 16);
}
DEV float bf2f(u16 h) {
  union { unsigned u; float f; } c; c.u = ((unsigned)h) << 16;
  return c.f;
}
// monotonic float<->uint key (for atomicMax on float values incl. negatives)
DEV unsigned fkey(float f) {
  unsigned u = __float_as_uint(f);
  return u ^ (unsigned)(((int)u >> 31) | 0x80000000);
}
DEV float unkey(unsigned k) {
  unsigned u = (k & 0x80000000u) ? (k ^ 0x80000000u) : ~k;
  return __uint_as_float(u);
}

#define SBAR_ __builtin_amdgcn_s_barrier()

// --- f32 -> bf16 bulk convert ----------------------------------------------
__global__ __launch_bounds__(256) void k_cvt(const float* __restrict__ in,
                                             u16* __restrict__ out, int n4) {
  int i = blockIdx.x * 256 + threadIdx.x;
  const int stride = gridDim.x * 256;
  for (; i < n4; i += stride) {
    float4 v = reinterpret_cast<const float4*>(in)[i];
    ushort4 o;
    o.x = f2bf(v.x); o.y = f2bf(v.y); o.z = f2bf(v.z); o.w = f2bf(v.w);
    reinterpret_cast<ushort4*>(out)[i] = o;
  }
}

// --- W (K,N) f32 -> W^T (N,K) bf16, 3 weights in one launch (z selects) ----
__global__ __launch_bounds__(256) void k_transw(const float* __restrict__ Wq,
                                                const float* __restrict__ Wk,
                                                const float* __restrict__ Wt,
                                                u16* __restrict__ Wqkt,
                                                u16* __restrict__ Wtt) {
  __shared__ float tile[32][33];
  const int z = blockIdx.z;
  const float* W = (z == 0) ? Wq : (z == 1) ? Wk : Wt;
  u16* D = (z == 0) ? Wqkt : (z == 1) ? (Wqkt + 1024 * 1024) : Wtt;
  const int bn = blockIdx.x, bk = blockIdx.y;
  const int tx = threadIdx.x & 31, ty = threadIdx.x >> 5;
#pragma unroll
  for (int j = 0; j < 4; ++j)
    tile[ty + j * 8][tx] = W[(size_t)(bk * 32 + ty + j * 8) * 1024 + bn * 32 + tx];
  __syncthreads();
#pragma unroll
  for (int j = 0; j < 4; ++j)
    D[(size_t)(bn * 32 + ty + j * 8) * 1024 + bk * 32 + tx] = f2bf(tile[tx][ty + j * 8]);
}

// --- Wbt[b][n][k] = bf16( Wtt[n][k] * pkr*pqr / (sumk*sumq) ) --------------
__global__ __launch_bounds__(256) void k_wbt(const u16* __restrict__ Wtt,
                                             const float* __restrict__ pkr,
                                             const float* __restrict__ pqr,
                                             const float* __restrict__ sumk,
                                             const float* __restrict__ sumq,
                                             u16* __restrict__ Wbt) {
  const int i = blockIdx.x * 256 + threadIdx.x;  // 1048576 threads
  const int k0 = (i & 127) * 8;
  const int n  = (i >> 7) & 1023;
  const int b  = i >> 17;
  const int hh = k0 >> 6;  // head of k-dim (8 elems stay in one head; DH=64)
  const float inv = 1.0f / (sumk[b * 16 + hh] * sumq[b * 16 + hh]);
  bf16x8 wv = *reinterpret_cast<const bf16x8*>(&Wtt[n * 1024 + k0]);
  bf16x8 o;
#pragma unroll
  for (int j = 0; j < 8; ++j) {
    const float p = pkr[b * 1024 + k0 + j] * pqr[b * 1024 + k0 + j] * inv;
    o[j] = (short)f2bf(bf2f((u16)wv[j]) * p);
  }
  *reinterpret_cast<bf16x8*>(&Wbt[(size_t)b * 1048576 + (size_t)n * 1024 + k0]) = o;
}

// --- 256x256 GEMM, m201 8-phase template, LDS-staged epilogue --------------
// C = A(Mx1024) x Bt(Nx1024)^T. 512 threads = 8 waves (2M x 4N), BK=64,
// double-buffered 128 KiB XOR-swizzled LDS. Iteration = 2 K-tiles, 8 phases,
// each phase: {ds_reads, 1 half-tile stage, barrier, lgkm0, 16 MFMA,
// barrier}. vmcnt(4) at P4/P8 only. Just-in-time staging (race-free by
// phase order: each LDS region's last reader retires >=1 barrier before the
// stage that overwrites it).
// EPI 0: bf16 out; block's cols land wholly in C0 (ci<gcols/2) or C1.
// EPI 2: f32 out = acc + bias0[col] + bf2f(extra[row,col]); Bt per-batch.
template <int EPI>
__global__ __launch_bounds__(512, 2) void k_gemm8(const u16* __restrict__ A,
                                                  const u16* __restrict__ Bt,
                                                  const float* __restrict__ bias0,
                                                  const float* __restrict__ bias1,
                                                  const u16* __restrict__ extra,
                                                  float* __restrict__ Cf,
                                                  u16* __restrict__ C0,
                                                  u16* __restrict__ C1,
                                                  int gcols) {
  __shared__ __align__(16) u16 lds[2 * 32768];  // [buf][A|B][256][64]
  const int tid = threadIdx.x;
  const int w = tid >> 6, lane = tid & 63;
  const int wm = w >> 2, wn = w & 3;

  // chunked XCD swizzle (nwg % 8 == 0)
  const int nwg = gridDim.x;
  const int swz = (blockIdx.x & 7) * (nwg >> 3) + (blockIdx.x >> 3);
  const int ci = swz % gcols, ri = swz / gcols;
  const int row0 = ri * 256, col0 = ci * 256;

  // staging: dest row = half*128 + p*64 + (tid>>3), slot = tid&7; source
  // pre-swizzled so physical slot s holds logical slot s ^ (row&7).
  const int sr = tid >> 3;
  const int ls8 = ((tid & 7) ^ (sr & 7)) * 8;
  const u16* gA = A + (size_t)(row0 + sr) * 1024 + ls8;
  const u16* gB;
  if (EPI == 2) {
    gB = Bt + (size_t)(row0 >> 12) * 1048576 + (size_t)(col0 + sr) * 1024 + ls8;
  } else {
    gB = Bt + (size_t)(col0 + sr) * 1024 + ls8;
  }

  auto stage = [&](int buf, int mat, int half, int kt, const u16* g) {
#pragma unroll
    for (int p = 0; p < 2; ++p) {
      const u16* src = g + (size_t)(half * 128 + p * 64) * 1024 + kt;
      u16* dst = (u16*)&lds[buf * 32768 + mat * 16384 + half * 8192 + p * 4096 + w * 512];
      __builtin_amdgcn_global_load_lds(
          (const __attribute__((address_space(1))) void*)src,
          (__attribute__((address_space(3))) void*)dst, 16, 0, 0);
    }
  };

  f32x4 acc[8][4] = {};

  // prologue: tile0 (A,B) -> buf0; B(1) -> buf1. A(1) staged at P1/P2.
  stage(0, 0, 0, 0, gA);
  stage(0, 0, 1, 0, gA);
  stage(0, 1, 0, 0, gB);
  stage(0, 1, 1, 0, gB);
  stage(1, 1, 0, 64, gB);
  stage(1, 1, 1, 64, gB);
  asm volatile("s_waitcnt vmcnt(4)" ::: "memory");  // tile0 landed; B(1) in flight
  SBAR_;

  const int lr15 = lane & 15, lhi = lane >> 4, lx = lane & 7;
  bf16x8 A0f[4][2], A1f[4][2], B0f[2][2], B1f[2][2];

#define RD_Ah(dst, base, half)                                                 \
  _Pragma("unroll") for (int mi = 0; mi < 4; ++mi)                             \
  _Pragma("unroll") for (int ks = 0; ks < 2; ++ks)                             \
    dst[mi][ks] = *reinterpret_cast<const bf16x8*>(                            \
        &(base)[(wm * 128 + (half) * 64 + mi * 16 + lr15) * 64 +               \
                (((ks << 2) | lhi) ^ lx) * 8]);
#define RD_Bh(dst, base, half)                                                 \
  _Pragma("unroll") for (int ni = 0; ni < 2; ++ni)                             \
  _Pragma("unroll") for (int ks = 0; ks < 2; ++ks)                             \
    dst[ni][ks] = *reinterpret_cast<const bf16x8*>(                            \
        &(base)[(wn * 64 + (half) * 32 + ni * 16 + lr15) * 64 +                \
                (((ks << 2) | lhi) ^ lx) * 8]);
#define MFMA_Q(ar, br, mo, no)                                                 \
  _Pragma("unroll") for (int mi = 0; mi < 4; ++mi)                             \
  _Pragma("unroll") for (int ni = 0; ni < 2; ++ni)                             \
  _Pragma("unroll") for (int ks = 0; ks < 2; ++ks)                             \
    acc[(mo) + mi][(no) + ni] = __builtin_amdgcn_mfma_f32_16x16x32_bf16(       \
        ar[mi][ks], br[ni][ks], acc[(mo) + mi][(no) + ni], 0, 0, 0);

#define LGKM0_ asm volatile("s_waitcnt lgkmcnt(0)" ::: "memory")
#define LGKM8_ asm volatile("s_waitcnt lgkmcnt(8)" ::: "memory")
#define PRIO1_ __builtin_amdgcn_s_setprio(1)
#define PRIO0_ __builtin_amdgcn_s_setprio(0)

  const u16* bA0 = &lds[0];
  const u16* bB0 = bA0 + 16384;
  const u16* bA1 = &lds[32768];
  const u16* bB1 = bA1 + 16384;

  for (int i = 0; i < 8; ++i) {
    const int t1k = (2 * i + 1) * 64;
    const int t2k = (2 * i + 2) * 64;
    const int t3k = (2 * i + 3) * 64;
    const bool pf = (i < 7);

    // ---- P1: read A0,B0 (tile 2i, buf0); stage A-h0(2i+1)->buf1 ----
    RD_Ah(A0f, bA0, 0);
    RD_Bh(B0f, bB0, 0);
    stage(1, 0, 0, t1k, gA);
    LGKM8_;
    SBAR_;
    LGKM0_;
    PRIO1_; MFMA_Q(A0f, B0f, 0, 0); PRIO0_;
    SBAR_;

    // ---- P2: read B1; stage A-h1(2i+1)->buf1 ----
    RD_Bh(B1f, bB0, 1);
    stage(1, 0, 1, t1k, gA);
    SBAR_;
    LGKM0_;
    PRIO1_; MFMA_Q(A0f, B1f, 0, 2); PRIO0_;
    SBAR_;

    // ---- P3: read A1; stage B-h0(2i+2)->buf0 (buf0.B retired @P2) ----
    RD_Ah(A1f, bA0, 1);
    if (pf) stage(0, 1, 0, t2k, gB);
    SBAR_;
    LGKM0_;
    PRIO1_; MFMA_Q(A1f, B1f, 4, 2); PRIO0_;
    SBAR_;

    // ---- P4: stage B-h1(2i+2)->buf0; vmcnt(4) retires tile 2i+1 ----
    if (pf) {
      stage(0, 1, 1, t2k, gB);
      asm volatile("s_waitcnt vmcnt(4)" ::: "memory");
    } else {
      asm volatile("s_waitcnt vmcnt(0)" ::: "memory");
    }
    SBAR_;
    PRIO1_; MFMA_Q(A1f, B0f, 4, 0); PRIO0_;
    SBAR_;

    // ---- P5: read A0,B0 (tile 2i+1, buf1); stage A-h0(2i+2)->buf0 ----
    RD_Ah(A0f, bA1, 0);
    RD_Bh(B0f, bB1, 0);
    if (pf) stage(0, 0, 0, t2k, gA);
    LGKM8_;
    SBAR_;
    LGKM0_;
    PRIO1_; MFMA_Q(A0f, B0f, 0, 0); PRIO0_;
    SBAR_;

    // ---- P6: read B1; stage A-h1(2i+2)->buf0 ----
    RD_Bh(B1f, bB1, 1);
    if (pf) stage(0, 0, 1, t2k, gA);
    SBAR_;
    LGKM0_;
    PRIO1_; MFMA_Q(A0f, B1f, 0, 2); PRIO0_;
    SBAR_;

    // ---- P7: read A1; stage B-h0(2i+3)->buf1 (buf1.B retired @P6) ----
    RD_Ah(A1f, bA1, 1);
    if (pf) stage(1, 1, 0, t3k, gB);
    SBAR_;
    LGKM0_;
    PRIO1_; MFMA_Q(A1f, B1f, 4, 2); PRIO0_;
    SBAR_;

    // ---- P8: stage B-h1(2i+3)->buf1; vmcnt(4) retires tile 2i+2 ----
    if (pf) {
      stage(1, 1, 1, t3k, gB);
      asm volatile("s_waitcnt vmcnt(4)" ::: "memory");
    }
    SBAR_;
    PRIO1_; MFMA_Q(A1f, B0f, 4, 0); PRIO0_;
    SBAR_;
  }
#undef RD_Ah
#undef RD_Bh
#undef MFMA_Q
#undef LGKM0_
#undef LGKM8_
#undef PRIO1_
#undef PRIO0_

  // ---- epilogue: LDS-staged coalesced stores (R4) ----
  if constexpr (EPI == 0) {
    u16* cl = (u16*)lds;
    const bool lo = (ci < (gcols >> 1));
    const float* bias = lo ? bias0 : bias1;
    u16* dst = lo ? C0 : C1;
    const int colloc0 = col0 - (lo ? 0 : 1024);
#pragma unroll
    for (int n = 0; n < 4; ++n) {
      const int cc = wn * 64 + n * 16 + lr15;
      const float bv = bias[colloc0 + cc];
#pragma unroll
      for (int m = 0; m < 8; ++m) {
        const int rb = wm * 128 + m * 16 + lhi * 4;
#pragma unroll
        for (int j = 0; j < 4; ++j) {
          const int r = rb + j;
          cl[r * 256 + (cc ^ ((r & 12) << 2))] = f2bf(acc[m][n][j] + bv);
        }
      }
    }
    __syncthreads();
#pragma unroll
    for (int pass = 0; pass < 16; ++pass) {
      const int idx = pass * 512 + tid;
      const int r = idx >> 5, g = idx & 31;
      bf16x8 v = *reinterpret_cast<const bf16x8*>(
          &cl[r * 256 + ((g * 8) ^ ((r & 12) << 2))]);
      *reinterpret_cast<bf16x8*>(
          &dst[(size_t)(row0 + r) * 1024 + colloc0 + g * 8]) = v;
    }
  } else {
    float* clf = (float*)lds;
#pragma unroll
    for (int half = 0; half < 2; ++half) {
      __syncthreads();
      if (wm == half) {
#pragma unroll
        for (int n = 0; n < 4; ++n) {
          const int cc = wn * 64 + n * 16 + lr15;
#pragma unroll
          for (int m = 0; m < 8; ++m) {
            const int rb = m * 16 + lhi * 4;
#pragma unroll
            for (int j = 0; j < 4; ++j) {
              const int r = rb + j;
              clf[r * 256 + (cc ^ ((r & 12) << 2))] = acc[m][n][j];
            }
          }
        }
      }
      __syncthreads();
#pragma unroll
      for (int pass = 0; pass < 16; ++pass) {
        const int idx = pass * 512 + tid;
        const int r = idx >> 6, g = idx & 63;
        f32x4 v = *reinterpret_cast<const f32x4*>(
            &clf[r * 256 + ((g * 4) ^ ((r & 12) << 2))]);
        const int grow = row0 + half * 128 + r;
        const int gcol = col0 + g * 4;
        ushort4 e = *reinterpret_cast<const ushort4*>(
            &extra[(size_t)grow * 1024 + gcol]);
        float4 o;
        o.x = v[0] + bias0[gcol + 0] + bf2f(e.x);
        o.y = v[1] + bias0[gcol + 1] + bf2f(e.y);
        o.z = v[2] + bias0[gcol + 2] + bf2f(e.z);
        o.w = v[3] + bias0[gcol + 3] + bf2f(e.w);
        *reinterpret_cast<float4*>(&Cf[(size_t)grow * 1024 + gcol]) = o;
      }
    }
  }
}

// --- score[b,h,s] = (X.Weff[:,h] + bias[h])*scale + mask; + running max ----
// HAS_PQ: Weff[d,h] = Wa[d,h] * pqr[b,d] / sumq[b, d>>6].
template <int HAS_PQ>
__global__ __launch_bounds__(256) void k_score(const u16* __restrict__ X,
                                               const float* __restrict__ Wa,
                                               const float* __restrict__ bias,
                                               const float* __restrict__ mask,
                                               const float* __restrict__ pqr,
                                               const float* __restrict__ sumq,
                                               float* __restrict__ score,
                                               unsigned* __restrict__ maxkey,
                                               float scale) {
  __shared__ float waT[16][1024];  // [h][d]
  __shared__ unsigned bmx[4][16];
  __shared__ float invs[16];
  const int b = blockIdx.y;
  if (HAS_PQ && threadIdx.x < 16) invs[threadIdx.x] = 1.0f / sumq[b * 16 + threadIdx.x];
  if (HAS_PQ) __syncthreads();
  for (int t = threadIdx.x; t < 16384; t += 256) {
    const int d = t >> 4, h = t & 15;
    float wv = Wa[t];
    if (HAS_PQ) wv *= pqr[b * 1024 + d] * invs[d >> 6];
    waT[h][d] = wv;
  }
  __syncthreads();
  const int w = threadIdx.x >> 6, l = threadIdx.x & 63;
  float rm = -3.0e38f;  // running max for this lane's h
  for (int g = blockIdx.x * 4 + w; g < 1024; g += gridDim.x * 4) {
    const size_t r0 = (size_t)b * 4096 + g * 4;
    float cur[64];  // idx = rr*16 + h
#pragma unroll
    for (int i = 0; i < 64; ++i) cur[i] = 0.f;
    for (int i = 0; i < 8; ++i) {
      const int d = i * 128 + l * 2;
      float xv[4][2];
#pragma unroll
      for (int rr = 0; rr < 4; ++rr) {
        ushort2 xq = *reinterpret_cast<const ushort2*>(&X[(r0 + rr) * 1024 + d]);
        xv[rr][0] = bf2f(xq.x); xv[rr][1] = bf2f(xq.y);
      }
#pragma unroll
      for (int h = 0; h < 16; ++h) {
        float2 wv = *reinterpret_cast<const float2*>(&waT[h][d]);
#pragma unroll
        for (int rr = 0; rr < 4; ++rr)
          cur[rr * 16 + h] += xv[rr][0] * wv.x + xv[rr][1] * wv.y;
      }
    }
#pragma unroll
    for (int s = 0; s < 6; ++s) {
      const int m = 1 << s;
      const int bit = (l >> s) & 1;
#pragma unroll
      for (int j = 0; j < (32 >> s); ++j) {
        const float mine = bit ? cur[2 * j + 1] : cur[2 * j];
        const float other = bit ? cur[2 * j] : cur[2 * j + 1];
        cur[j] = mine + __shfl_xor(other, m, 64);
      }
    }
    const int rr = l >> 4, h = l & 15;
    const int si = g * 4 + rr;
    const float v = (cur[0] + bias[h]) * scale + mask[b * 4096 + si];
    score[((size_t)b * 16 + h) * 4096 + si] = v;
    rm = fmaxf(rm, v);
  }
  // reduce rm over the 4 rr-lane groups (same h at l, l^16, l^32)
  rm = fmaxf(rm, __shfl_xor(rm, 16, 64));
  rm = fmaxf(rm, __shfl_xor(rm, 32, 64));
  if (l < 16) bmx[w][l] = fkey(rm);
  __syncthreads();
  if (threadIdx.x < 16) {
    unsigned k = bmx[0][threadIdx.x];
    k = max(k, bmx[1][threadIdx.x]);
    k = max(k, bmx[2][threadIdx.x]);
    k = max(k, bmx[3][threadIdx.x]);
    atomicMax(&maxkey[b * 16 + threadIdx.x], k);
  }
}

// --- pool: w = exp(score-max); pooled_raw[b,d] += sum_s w*X; sum[b,h] += w --
__global__ __launch_bounds__(256) void k_pool(const float* __restrict__ score,
                                              const unsigned* __restrict__ maxkey,
                                              const u16* __restrict__ X,
                                              float* __restrict__ pooled,
                                              float* __restrict__ sumexp) {
  __shared__ float wl[16][132];
  const int b = blockIdx.x >> 5, c = blockIdx.x & 31;
  const int s0 = c * 128;
  for (int t = threadIdx.x; t < 2048; t += 256) {
    const int h = t >> 7, si = t & 127;
    const float mx = unkey(maxkey[b * 16 + h]);
    wl[h][si] = __expf(score[((size_t)b * 16 + h) * 4096 + s0 + si] - mx);
  }
  __syncthreads();
  // block-partial sumexp: thread t: h=t>>4, part=t&15 sums 8 elems
  {
    const int h = threadIdx.x >> 4, part = threadIdx.x & 15;
    float s = 0.f;
#pragma unroll
    for (int j = 0; j < 8; ++j) s += wl[h][part * 8 + j];
#pragma unroll
    for (int m = 1; m < 16; m <<= 1) s += __shfl_xor(s, m, 64);
    if (part == 0) atomicAdd(&sumexp[b * 16 + h], s);
  }
  const int d0 = threadIdx.x * 4, h = threadIdx.x >> 4;
  float a0 = 0, a1 = 0, a2 = 0, a3 = 0;
#pragma unroll 4
  for (int si = 0; si < 128; ++si) {
    const float wv = wl[h][si];
    const size_t base = ((size_t)b * 4096 + s0 + si) * 1024 + d0;
    ushort4 xq = *reinterpret_cast<const ushort4*>(X + base);
    a0 += wv * bf2f(xq.x); a1 += wv * bf2f(xq.y);
    a2 += wv * bf2f(xq.z); a3 += wv * bf2f(xq.w);
  }
  atomicAdd(&pooled[b * 1024 + d0 + 0], a0);
  atomicAdd(&pooled[b * 1024 + d0 + 1], a1);
  atomicAdd(&pooled[b * 1024 + d0 + 2], a2);
  atomicAdd(&pooled[b * 1024 + d0 + 3], a3);
}

// ---------------------------------------------------------------------------
extern "C" void kernel_launch(void* const* d_in, const int* in_sizes, int n_in,
                              void* d_out, int out_size, void* d_ws, size_t ws_size,
                              hipStream_t stream) {
  (void)in_sizes; (void)n_in; (void)out_size; (void)ws_size;
  const float* x    = (const float*)d_in[0];
  const float* mask = (const float*)d_in[1];
  const float* Wq   = (const float*)d_in[2];
  const float* bq   = (const float*)d_in[3];
  const float* Wqa  = (const float*)d_in[4];
  const float* bqa  = (const float*)d_in[5];
  const float* Wk   = (const float*)d_in[6];
  const float* bk   = (const float*)d_in[7];
  const float* Wka  = (const float*)d_in[8];
  const float* bka  = (const float*)d_in[9];
  const float* Wt   = (const float*)d_in[10];
  const float* bt   = (const float*)d_in[11];
  float* out = (float*)d_out;
  char* ws = (char*)d_ws;

  size_t off = 0;
  auto take = [&](size_t b) { char* p = ws + off; off += (b + 255) & ~(size_t)255; return p; };
  u16*   xb    = (u16*)  take(67108864);   // x bf16
  u16*   qb    = (u16*)  take(67108864);   // q bf16
  u16*   kb    = (u16*)  take(67108864);   // k bf16
  u16*   Wqkt  = (u16*)  take(4194304);    // [Wq^T ; Wk^T] (2048 x 1024) bf16
  u16*   Wtt   = (u16*)  take(2097152);    // Wt^T bf16
  u16*   Wbt   = (u16*)  take(16777216);   // per-batch out weights (8x1024x1024)
  float* sc    = (float*)take(2097152);    // (B,H,S) scores
  // contiguous zero-init block: pq_raw, pk_raw, sumq, sumk, maxq, maxk
  char*  nb    = take(68608);
  float*    pqr  = (float*)nb;               // 32768 B
  float*    pkr  = (float*)(nb + 32768);     // 32768 B
  float*    sumq = (float*)(nb + 65536);     // 512 B
  float*    sumk = (float*)(nb + 66048);     // 512 B
  unsigned* maxq = (unsigned*)(nb + 66560);  // 512 B
  unsigned* maxk = (unsigned*)(nb + 67072);  // 512 B

  // prep
  k_cvt<<<2048, 256, 0, stream>>>(x, xb, 8388608);
  k_transw<<<dim3(32, 32, 3), 256, 0, stream>>>(Wq, Wk, Wt, Wqkt, Wtt);
  hipMemsetAsync(nb, 0, 68608, stream);

  // fused q,k = x @ [Wq|Wk] + [bq|bk]
  k_gemm8<0><<<1024, 512, 0, stream>>>(xb, Wqkt, bq, bk, nullptr, nullptr, qb, kb, 8);

  // q path: score (+max), pool (+sumexp)
  k_score<0><<<dim3(128, 8), 256, 0, stream>>>(qb, Wqa, bqa, mask, nullptr, nullptr,
                                               sc, maxq, 0.125f);
  k_pool<<<256, 256, 0, stream>>>(sc, maxq, qb, pqr, sumq);

  // k path (mixed_qk factored out; 1/sumq folded into Weff)
  k_score<1><<<dim3(128, 8), 256, 0, stream>>>(kb, Wka, bka, mask, pqr, sumq,
                                               sc, maxk, 0.125f);
  k_pool<<<256, 256, 0, stream>>>(sc, maxk, kb, pkr, sumk);

  // out = q @ W_b + bt + q, W_b = diag(pkr*pqr/(sumk*sumq)) @ Wt per batch
  k_wbt<<<4096, 256, 0, stream>>>(Wtt, pkr, pqr, sumk, sumq, Wbt);
  k_gemm8<2><<<512, 512, 0, stream>>>(qb, Wbt, bt, nullptr, qb, out, nullptr, nullptr, 4);
}